// Round 6
// baseline (60.862 us; speedup 1.0000x reference)
//
#include <hip/hip_runtime.h>

#define NIMG 8
#define H 2048
#define W 2048
#define AH 64
#define AW 64
#define PAD 992        // (W - AW) / 2
#define CH 32          // rows per wave -> 4096 waves, 16 waves/CU

typedef float f4 __attribute__((ext_vector_type(4)));

__device__ __forceinline__ float rl(float v, int k) {
    return __int_as_float(__builtin_amdgcn_readlane(__float_as_int(v), k));
}

// load one float4 of a (wrapped) row, with action-XOR applied
__device__ __forceinline__ f4 load_row(const float* __restrict__ uni,
                                       const float* __restrict__ act,
                                       size_t img, int r, int c) {
    r &= (H - 1);
    f4 v = *reinterpret_cast<const f4*>(uni + img + (size_t)r * W + c);
    if (r >= PAD && r < PAD + AH && c >= PAD && c < PAD + AW) {
        const float* a = act + (r - PAD) * AW + (c - PAD);
        v.x = (v.x != a[0]) ? 1.0f : 0.0f;
        v.y = (v.y != a[1]) ? 1.0f : 0.0f;
        v.z = (v.z != a[2]) ? 1.0f : 0.0f;
        v.w = (v.w != a[3]) ? 1.0f : 0.0f;
    }
    return v;
}

__device__ __forceinline__ f4 make_hs(f4 v, int lane, float hl, float hr) {
    float left  = __shfl_up(v.w, 1);
    float right = __shfl_down(v.x, 1);
    if (lane == 0)  left  = hl;
    if (lane == 63) right = hr;
    f4 hs;
    hs.x = left  + v.x + v.y;
    hs.y = v.x + v.y + v.z;
    hs.z = v.y + v.z + v.w;
    hs.w = v.z + v.w + right;
    return hs;
}

// next = (nbr==3) || (nbr==2 && alive)  <=>  |nbr - 3 + 0.5*alive| <= 0.5 (exact)
__device__ __forceinline__ f4 life(f4 a, f4 b, f4 c, f4 cen, float keep) {
    f4 nbr3 = a + b + c - cen;
    nbr3.x -= 3.0f; nbr3.y -= 3.0f; nbr3.z -= 3.0f; nbr3.w -= 3.0f;
    f4 o;
    o.x = (__builtin_fabsf(__builtin_fmaf(0.5f, cen.x, nbr3.x)) <= 0.5f) ? keep : 0.0f;
    o.y = (__builtin_fabsf(__builtin_fmaf(0.5f, cen.y, nbr3.y)) <= 0.5f) ? keep : 0.0f;
    o.z = (__builtin_fabsf(__builtin_fmaf(0.5f, cen.z, nbr3.z)) <= 0.5f) ? keep : 0.0f;
    o.w = (__builtin_fabsf(__builtin_fmaf(0.5f, cen.w, nbr3.w)) <= 0.5f) ? keep : 0.0f;
    return o;
}

__global__ __launch_bounds__(256, 8) void carle_life_kernel(
        const float* __restrict__ uni,
        const float* __restrict__ act,
        float* __restrict__ out) {
    __shared__ float red[4];
    const int t    = threadIdx.x;
    const int lane = t & 63;
    const int wvid = t >> 6;

    // XCD-contiguous swizzle over 1024 blocks: each XCD owns one image
    const int bid = blockIdx.x;
    const int sb  = ((bid & 7) << 7) | (bid >> 3);    // bijective on [0,1024)
    const int wv  = (sb << 2) | wvid;                 // 0..4095
    const int n   = wv >> 9;                          // image (512 waves/img)
    const int rem = wv & 511;
    const int sx  = rem & 7;                          // col strip (256 wide)
    const int sy  = rem >> 3;                         // row chunk 0..63
    const int strip = sx << 8;
    const int y0  = sy * CH;
    const int c   = strip + (lane << 2);
    const size_t img = (size_t)n * (size_t)H * (size_t)W;

    // ---- preload 8 rows (k = 0..7, rows y0-1 .. y0+6) ----
    f4 vA = load_row(uni, act, img, y0 - 1, c);
    f4 vB = load_row(uni, act, img, y0,     c);
    f4 b1 = load_row(uni, act, img, y0 + 1, c);
    f4 b2 = load_row(uni, act, img, y0 + 2, c);
    f4 b3 = load_row(uni, act, img, y0 + 3, c);
    f4 b4 = load_row(uni, act, img, y0 + 4, c);
    f4 b5 = load_row(uni, act, img, y0 + 5, c);
    f4 b6 = load_row(uni, act, img, y0 + 6, c);

    // ---- halo columns: lanes 0..33 load left and right col for 34 rows ----
    float haloL = 0.0f, haloR = 0.0f;
    if (lane < CH + 2) {
        const int r = (y0 - 1 + lane) & (H - 1);
        const bool arow = (r >= PAD && r < PAD + AH);
        int hc = (strip - 1) & (W - 1);
        float x = uni[img + (size_t)r * W + hc];
        if (arow && hc >= PAD && hc < PAD + AW)
            x = (x != act[(r - PAD) * AW + (hc - PAD)]) ? 1.0f : 0.0f;
        haloL = x;
        hc = (strip + 256) & (W - 1);
        x = uni[img + (size_t)r * W + hc];
        if (arow && hc >= PAD && hc < PAD + AW)
            x = (x != act[(r - PAD) * AW + (hc - PAD)]) ? 1.0f : 0.0f;
        haloR = x;
    }

    // ---- fused reset flag: sum(action) == 4096 (overlaps the row loads) ----
    {
        const f4* a4 = reinterpret_cast<const f4*>(act);
        float s = 0.0f;
        #pragma unroll
        for (int j = 0; j < 4; ++j) {
            f4 a = a4[t * 4 + j];
            s += a.x + a.y + a.z + a.w;
        }
        #pragma unroll
        for (int k = 32; k > 0; k >>= 1) s += __shfl_down(s, k);
        if (lane == 0) red[wvid] = s;
    }
    __syncthreads();
    const float keep =
        ((red[0] + red[1] + red[2] + red[3]) == (float)(AH * AW)) ? 0.0f : 1.0f;

    // ---- steady state: 1 row/iter, prefetch distance 6 ----
    f4 hsA = make_hs(vA, lane, rl(haloL, 0), rl(haloR, 0));
    f4 hsB = make_hs(vB, lane, rl(haloL, 1), rl(haloR, 1));
    f4 cen = vB;

    #pragma unroll
    for (int i = 0; i < CH; ++i) {
        f4 bn;
        const bool ld = (i + 8 < CH + 2);              // row k=i+8 exists
        if (ld) bn = load_row(uni, act, img, y0 + i + 7, c);

        const f4 hsC = make_hs(b1, lane, rl(haloL, i + 2), rl(haloR, i + 2));
        const f4 o   = life(hsA, hsB, hsC, cen, keep);
        __builtin_nontemporal_store(o,
            reinterpret_cast<f4*>(out + img + (size_t)(y0 + i) * W + c));

        hsA = hsB; hsB = hsC; cen = b1;
        b1 = b2; b2 = b3; b3 = b4; b4 = b5; b5 = b6;
        if (ld) b6 = bn;
    }
}

extern "C" void kernel_launch(void* const* d_in, const int* in_sizes, int n_in,
                              void* d_out, int out_size, void* d_ws, size_t ws_size,
                              hipStream_t stream) {
    const float* uni = (const float*)d_in[0];   // (8,1,2048,2048) f32
    const float* act = (const float*)d_in[1];   // (1,1,64,64) f32
    float* outp = (float*)d_out;
    (void)d_ws;

    carle_life_kernel<<<NIMG * 8 * (H / CH) / 4, 256, 0, stream>>>(uni, act, outp);
}

// Round 7
// 49.203 us; speedup vs baseline: 1.2370x; 1.2370x over previous
//
#include <hip/hip_runtime.h>

#define NIMG 8
#define H 2048
#define W 2048
#define AH 64
#define AW 64
#define PAD 992        // (W - AW) / 2
#define CH 16          // rows per wave -> 8192 waves -> 8/SIMD, all-resident

typedef float f4 __attribute__((ext_vector_type(4)));

__device__ __forceinline__ float rl(float v, int k) {
    return __int_as_float(__builtin_amdgcn_readlane(__float_as_int(v), k));
}

// load one float4 of a (wrapped) row, with action-XOR applied
__device__ __forceinline__ f4 load_row(const float* __restrict__ uni,
                                       const float* __restrict__ act,
                                       size_t img, int r, int c) {
    r &= (H - 1);
    f4 v = *reinterpret_cast<const f4*>(uni + img + (size_t)r * W + c);
    if (r >= PAD && r < PAD + AH && c >= PAD && c < PAD + AW) {
        const float* a = act + (r - PAD) * AW + (c - PAD);
        v.x = (v.x != a[0]) ? 1.0f : 0.0f;
        v.y = (v.y != a[1]) ? 1.0f : 0.0f;
        v.z = (v.z != a[2]) ? 1.0f : 0.0f;
        v.w = (v.w != a[3]) ? 1.0f : 0.0f;
    }
    return v;
}

__device__ __forceinline__ f4 make_hs(f4 v, int lane, float hl, float hr) {
    float left  = __shfl_up(v.w, 1);
    float right = __shfl_down(v.x, 1);
    if (lane == 0)  left  = hl;
    if (lane == 63) right = hr;
    f4 hs;
    hs.x = left  + v.x + v.y;
    hs.y = v.x + v.y + v.z;
    hs.z = v.y + v.z + v.w;
    hs.w = v.z + v.w + right;
    return hs;
}

// next = (nbr==3) || (nbr==2 && alive)  <=>  |nbr - 3 + 0.5*alive| <= 0.5 (exact)
__device__ __forceinline__ f4 life(f4 a, f4 b, f4 c, f4 cen, float keep) {
    f4 nbr3 = a + b + c - cen;
    nbr3.x -= 3.0f; nbr3.y -= 3.0f; nbr3.z -= 3.0f; nbr3.w -= 3.0f;
    f4 o;
    o.x = (__builtin_fabsf(__builtin_fmaf(0.5f, cen.x, nbr3.x)) <= 0.5f) ? keep : 0.0f;
    o.y = (__builtin_fabsf(__builtin_fmaf(0.5f, cen.y, nbr3.y)) <= 0.5f) ? keep : 0.0f;
    o.z = (__builtin_fabsf(__builtin_fmaf(0.5f, cen.z, nbr3.z)) <= 0.5f) ? keep : 0.0f;
    o.w = (__builtin_fabsf(__builtin_fmaf(0.5f, cen.w, nbr3.w)) <= 0.5f) ? keep : 0.0f;
    return o;
}

__global__ __launch_bounds__(256, 8) void carle_life_kernel(
        const float* __restrict__ uni,
        const float* __restrict__ act,
        float* __restrict__ out) {
    __shared__ float red[4];
    const int t    = threadIdx.x;
    const int lane = t & 63;
    const int wvid = t >> 6;

    // XCD-contiguous swizzle: each XCD (bid&7) owns one image, walked in sy order
    const int bid = blockIdx.x;
    const int sb  = ((bid & 7) << 8) | (bid >> 3);    // bijective on [0,2048)
    const int wv  = (sb << 2) | wvid;                 // 0..8191
    const int n   = wv >> 10;                         // image (1024 waves/img)
    const int rem = wv & 1023;
    const int sx  = rem & 7;                          // col strip (256 wide)
    const int sy  = rem >> 3;                         // row chunk (16 tall)
    const int strip = sx << 8;
    const int y0  = sy * CH;
    const int c   = strip + (lane << 2);
    const size_t img = (size_t)n * (size_t)H * (size_t)W;

    // ---- first-needed rows + halo columns issued first ----
    f4 vA = load_row(uni, act, img, y0 - 1, c);
    f4 vB = load_row(uni, act, img, y0,     c);

    // batched halo columns: lanes 0..17 left col, lanes 32..49 right col
    const int hr   = lane & 31;
    const int hcol = (lane < 32) ? ((strip - 1) & (W - 1))
                                 : ((strip + 256) & (W - 1));
    float halo = 0.0f;
    if (hr < CH + 2) {
        const int r = (y0 - 1 + hr) & (H - 1);
        float x = uni[img + (size_t)r * W + hcol];
        if (r >= PAD && r < PAD + AH && hcol >= PAD && hcol < PAD + AW)
            x = (x != act[(r - PAD) * AW + (hcol - PAD)]) ? 1.0f : 0.0f;
        halo = x;
    }

    // ---- bulk preload: rows y0+1 .. y0+6 (pipeline depth 8) ----
    f4 b1 = load_row(uni, act, img, y0 + 1, c);
    f4 b2 = load_row(uni, act, img, y0 + 2, c);
    f4 b3 = load_row(uni, act, img, y0 + 3, c);
    f4 b4 = load_row(uni, act, img, y0 + 4, c);
    f4 b5 = load_row(uni, act, img, y0 + 5, c);
    f4 b6 = load_row(uni, act, img, y0 + 6, c);

    // ---- fused reset flag: sum(action) == 4096 (overlaps the row loads) ----
    {
        const f4* a4 = reinterpret_cast<const f4*>(act);
        float s = 0.0f;
        #pragma unroll
        for (int j = 0; j < 4; ++j) {
            f4 a = a4[t * 4 + j];
            s += a.x + a.y + a.z + a.w;
        }
        #pragma unroll
        for (int k = 32; k > 0; k >>= 1) s += __shfl_down(s, k);
        if (lane == 0) red[wvid] = s;
    }
    __syncthreads();
    const float keep =
        ((red[0] + red[1] + red[2] + red[3]) == (float)(AH * AW)) ? 0.0f : 1.0f;

    // ---- steady state: 1 row/iter, prefetch distance 6 ----
    f4 hsA = make_hs(vA, lane, rl(halo, 0), rl(halo, 32));
    f4 hsB = make_hs(vB, lane, rl(halo, 1), rl(halo, 33));
    f4 cen = vB;

    #pragma unroll
    for (int i = 0; i < CH; ++i) {
        f4 bn;
        const bool ld = (i + 8 < CH + 2);              // row k=i+8 exists
        if (ld) bn = load_row(uni, act, img, y0 + i + 7, c);

        const f4 hsC = make_hs(b1, lane, rl(halo, i + 2), rl(halo, 32 + i + 2));
        const f4 o   = life(hsA, hsB, hsC, cen, keep);
        __builtin_nontemporal_store(o,
            reinterpret_cast<f4*>(out + img + (size_t)(y0 + i) * W + c));

        hsA = hsB; hsB = hsC; cen = b1;
        b1 = b2; b2 = b3; b3 = b4; b4 = b5; b5 = b6;
        if (ld) b6 = bn;
    }
}

extern "C" void kernel_launch(void* const* d_in, const int* in_sizes, int n_in,
                              void* d_out, int out_size, void* d_ws, size_t ws_size,
                              hipStream_t stream) {
    const float* uni = (const float*)d_in[0];   // (8,1,2048,2048) f32
    const float* act = (const float*)d_in[1];   // (1,1,64,64) f32
    float* outp = (float*)d_out;
    (void)d_ws;

    carle_life_kernel<<<NIMG * 8 * (H / CH) / 4, 256, 0, stream>>>(uni, act, outp);
}

// Round 8
// 46.847 us; speedup vs baseline: 1.2992x; 1.0503x over previous
//
#include <hip/hip_runtime.h>

#define NIMG 8
#define H 2048
#define W 2048
#define AH 64
#define AW 64
#define PAD 992        // (W - AW) / 2
#define CH 16          // rows per wave -> 8192 waves -> 8/SIMD

typedef float f4 __attribute__((ext_vector_type(4)));

__device__ __forceinline__ float rl(float v, int k) {
    return __int_as_float(__builtin_amdgcn_readlane(__float_as_int(v), k));
}

// load one float4 of a (wrapped) row, with action-XOR applied
__device__ __forceinline__ f4 load_row(const float* __restrict__ uni,
                                       const float* __restrict__ act,
                                       size_t img, int r, int c) {
    r &= (H - 1);
    f4 v = *reinterpret_cast<const f4*>(uni + img + (size_t)r * W + c);
    if (r >= PAD && r < PAD + AH && c >= PAD && c < PAD + AW) {
        const float* a = act + (r - PAD) * AW + (c - PAD);
        v.x = (v.x != a[0]) ? 1.0f : 0.0f;
        v.y = (v.y != a[1]) ? 1.0f : 0.0f;
        v.z = (v.z != a[2]) ? 1.0f : 0.0f;
        v.w = (v.w != a[3]) ? 1.0f : 0.0f;
    }
    return v;
}

__device__ __forceinline__ f4 make_hs(f4 v, int lane, float hl, float hr) {
    float left  = __shfl_up(v.w, 1);
    float right = __shfl_down(v.x, 1);
    if (lane == 0)  left  = hl;
    if (lane == 63) right = hr;
    f4 hs;
    hs.x = left  + v.x + v.y;
    hs.y = v.x + v.y + v.z;
    hs.z = v.y + v.z + v.w;
    hs.w = v.z + v.w + right;
    return hs;
}

// next = (nbr==3) || (nbr==2 && alive)  <=>  |nbr - 3 + 0.5*alive| <= 0.5 (exact)
__device__ __forceinline__ f4 life(f4 a, f4 b, f4 c, f4 cen, float keep) {
    f4 nbr3 = a + b + c - cen;
    nbr3.x -= 3.0f; nbr3.y -= 3.0f; nbr3.z -= 3.0f; nbr3.w -= 3.0f;
    f4 o;
    o.x = (__builtin_fabsf(__builtin_fmaf(0.5f, cen.x, nbr3.x)) <= 0.5f) ? keep : 0.0f;
    o.y = (__builtin_fabsf(__builtin_fmaf(0.5f, cen.y, nbr3.y)) <= 0.5f) ? keep : 0.0f;
    o.z = (__builtin_fabsf(__builtin_fmaf(0.5f, cen.z, nbr3.z)) <= 0.5f) ? keep : 0.0f;
    o.w = (__builtin_fabsf(__builtin_fmaf(0.5f, cen.w, nbr3.w)) <= 0.5f) ? keep : 0.0f;
    return o;
}

__global__ __launch_bounds__(256, 8) void carle_life_kernel(
        const float* __restrict__ uni,
        const float* __restrict__ act,
        float* __restrict__ out) {
    __shared__ float red[4];
    const int t    = threadIdx.x;
    const int lane = t & 63;
    const int wvid = t >> 6;

    // XCD-contiguous swizzle: each XCD (bid&7) owns one image, walked in sy order
    const int bid = blockIdx.x;
    const int sb  = ((bid & 7) << 8) | (bid >> 3);    // bijective on [0,2048)
    const int wv  = (sb << 2) | wvid;                 // 0..8191
    const int n   = wv >> 10;                         // image (1024 waves/img)
    const int rem = wv & 1023;
    const int sx  = rem & 7;                          // col strip (256 wide)
    const int sy  = rem >> 3;                         // row chunk (16 tall)
    const int strip = sx << 8;
    const int y0  = sy * CH;
    const int c   = strip + (lane << 2);
    const size_t img = (size_t)n * (size_t)H * (size_t)W;

    // ---- preload 7 rows (k = 0..6, rows y0-1 .. y0+5): max head start ----
    f4 vA = load_row(uni, act, img, y0 - 1, c);
    f4 vB = load_row(uni, act, img, y0,     c);
    f4 b1 = load_row(uni, act, img, y0 + 1, c);
    f4 b2 = load_row(uni, act, img, y0 + 2, c);
    f4 b3 = load_row(uni, act, img, y0 + 3, c);
    f4 b4 = load_row(uni, act, img, y0 + 4, c);
    f4 b5 = load_row(uni, act, img, y0 + 5, c);

    // ---- batched halo columns: lanes 0..17 left col, lanes 32..49 right ----
    const int hr   = lane & 31;
    const int hcol = (lane < 32) ? ((strip - 1) & (W - 1))
                                 : ((strip + 256) & (W - 1));
    float halo = 0.0f;
    if (hr < CH + 2) {
        const int r = (y0 - 1 + hr) & (H - 1);
        float x = uni[img + (size_t)r * W + hcol];
        if (r >= PAD && r < PAD + AH && hcol >= PAD && hcol < PAD + AW)
            x = (x != act[(r - PAD) * AW + (hcol - PAD)]) ? 1.0f : 0.0f;
        halo = x;
    }

    // ---- fused reset flag: sum(action) == 4096 (overlaps the row loads) ----
    {
        const f4* a4 = reinterpret_cast<const f4*>(act);
        float s = 0.0f;
        #pragma unroll
        for (int j = 0; j < 4; ++j) {
            f4 a = a4[t * 4 + j];
            s += a.x + a.y + a.z + a.w;
        }
        #pragma unroll
        for (int k = 32; k > 0; k >>= 1) s += __shfl_down(s, k);
        if (lane == 0) red[wvid] = s;
    }
    __syncthreads();
    const float keep =
        ((red[0] + red[1] + red[2] + red[3]) == (float)(AH * AW)) ? 0.0f : 1.0f;

    // ---- steady state: 1 row/iter, prefetch distance 5 (≈6 loads in flight)
    f4 hsA = make_hs(vA, lane, rl(halo, 0), rl(halo, 32));
    f4 hsB = make_hs(vB, lane, rl(halo, 1), rl(halo, 33));
    f4 cen = vB;

    #pragma unroll
    for (int i = 0; i < CH; ++i) {
        f4 bn;
        const bool ld = (i + 7 < CH + 2);              // row k=i+7 exists
        if (ld) bn = load_row(uni, act, img, y0 + i + 6, c);

        const f4 hsC = make_hs(b1, lane, rl(halo, i + 2), rl(halo, 32 + i + 2));
        const f4 o   = life(hsA, hsB, hsC, cen, keep);
        __builtin_nontemporal_store(o,
            reinterpret_cast<f4*>(out + img + (size_t)(y0 + i) * W + c));

        hsA = hsB; hsB = hsC; cen = b1;
        b1 = b2; b2 = b3; b3 = b4; b4 = b5;
        if (ld) b5 = bn;
    }
}

extern "C" void kernel_launch(void* const* d_in, const int* in_sizes, int n_in,
                              void* d_out, int out_size, void* d_ws, size_t ws_size,
                              hipStream_t stream) {
    const float* uni = (const float*)d_in[0];   // (8,1,2048,2048) f32
    const float* act = (const float*)d_in[1];   // (1,1,64,64) f32
    float* outp = (float*)d_out;
    (void)d_ws;

    carle_life_kernel<<<NIMG * 8 * (H / CH) / 4, 256, 0, stream>>>(uni, act, outp);
}